// Round 7
// baseline (116.516 us; speedup 1.0000x reference)
//
#include <hip/hip_runtime.h>

// Problem constants
#define NB   16
#define CIN  256
#define COUT 256
#define HH   32
#define WW   32
#define HW   1024           // 32*32
#define KK   9
#define CK   2304           // CIN*KK  (ordered k*256 + c, tap-major)

typedef __bf16 bf16x8 __attribute__((ext_vector_type(8)));
typedef float  f32x4  __attribute__((ext_vector_type(4)));

__device__ __forceinline__ unsigned short f2bf(float f) {
    unsigned int u = __float_as_uint(f);
    u += 0x7FFFu + ((u >> 16) & 1u);          // round-nearest-even
    return (unsigned short)(u >> 16);
}
__device__ __forceinline__ float bfhi(unsigned int u) {   // high bf16 -> f32
    return __uint_as_float(u & 0xFFFF0000u);
}
__device__ __forceinline__ float bflo(unsigned int u) {   // low bf16 -> f32
    return __uint_as_float(u << 16);
}
// pack two f32 -> one dword of 2x bf16 (RNE). No builtin on gfx950 (ROCm 7.2)
// — inline asm v_cvt_pk_bf16_f32: src0 -> low 16, src1 -> high 16.
__device__ __forceinline__ unsigned pk2(float lo, float hi) {
    unsigned r;
    asm("v_cvt_pk_bf16_f32 %0, %1, %2" : "=v"(r) : "v"(lo), "v"(hi));
    return r;
}

typedef const __attribute__((address_space(1))) void* gas_ptr;
typedef __attribute__((address_space(3))) void* las_ptr;

__device__ __forceinline__ void async16(const void* g, void* l) {
    __builtin_amdgcn_global_load_lds((gas_ptr)g, (las_ptr)l, 16, 0, 0);
}

#define SB() __builtin_amdgcn_sched_barrier(0)
// Raw barrier: LDS-visibility only (B ds_write + frag reads). vmcnt is never
// drained to 0 in the loop — DMA completion is enforced by the counted
// vmcnt at step entry (below).
#define SYNC() do { SB(); asm volatile("s_waitcnt lgkmcnt(0)" ::: "memory"); SB(); \
                    __builtin_amdgcn_s_barrier(); SB(); } while (0)
// Counted VMEM waits (T4). At step entry, outstanding = [offp 0/1] + dma(8)
// + loadc(8).  vmcnt(8) drains the 8 DMA loads (they are always older than
// the trailing loadc batch) without waiting the fresh gathers.  The final
// step has no trailing loadc -> vmcnt(0).
#define VM8() do { SB(); asm volatile("s_waitcnt vmcnt(8)" ::: "memory"); SB(); } while (0)
#define VM0() do { SB(); asm volatile("s_waitcnt vmcnt(0)" ::: "memory"); SB(); } while (0)

// ----------------------------------------------------------------- prep ----
// One kernel, two roles (saves a launch and runs them concurrently):
//   blocks [0,256):    weight fp32 [O][C][3][3] -> bf16 [O][k*256+c]
//   blocks [256,1280): x fp32 [n][c][hw] -> xtb bf16 [n][hw][c] (64x64 tiles)
// Grid-barrier mono fusion measured WORSE (round 3) — keep two dispatches.
__global__ __launch_bounds__(256) void prep_kernel(const float* __restrict__ w,
                                                   unsigned short* __restrict__ wbf,
                                                   const float* __restrict__ x,
                                                   unsigned short* __restrict__ xtb) {
    __shared__ float lsbuf[64 * 65];
    const int t = threadIdx.x;

    if (blockIdx.x < 256) {
        // ---- wconv role
        const int o = blockIdx.x;
        const float* wo = w + (size_t)o * CK;
#pragma unroll
        for (int i = t; i < CK; i += 256) lsbuf[i] = wo[i];
        __syncthreads();
        unsigned short* dst = wbf + (size_t)o * CK;
#pragma unroll
        for (int i = t; i < CK; i += 256) {
            int k = i >> 8, c = i & 255;
            dst[i] = f2bf(lsbuf[c * KK + k]);     // bank stride 9: conflict-free
        }
        return;
    }

    // ---- xt role
    float (*ls)[65] = (float(*)[65])lsbuf;
    const int id  = blockIdx.x - 256;
    const int c0  = (id & 3) << 6;
    const int hw0 = ((id >> 2) & 15) << 6;
    const int n   = id >> 6;
    {
        int c = t >> 2, q = t & 3;
        const float4* base = (const float4*)(x + ((size_t)(n * CIN + c0 + c)) * HW + hw0 + q * 16);
#pragma unroll
        for (int j = 0; j < 4; ++j) {
            float4 v = base[j];
            ls[c][q * 16 + j * 4 + 0] = v.x;
            ls[c][q * 16 + j * 4 + 1] = v.y;
            ls[c][q * 16 + j * 4 + 2] = v.z;
            ls[c][q * 16 + j * 4 + 3] = v.w;
        }
    }
    __syncthreads();
    {
        int hw = t >> 2, seg = (t & 3) * 16;
        unsigned int dw[8];
#pragma unroll
        for (int j = 0; j < 8; ++j) {
            float f0 = ls[seg + 2 * j][hw];
            float f1 = ls[seg + 2 * j + 1][hw];
            dw[j] = (unsigned)f2bf(f0) | ((unsigned)f2bf(f1) << 16);
        }
        uint4* dst = (uint4*)(xtb + ((size_t)(n * HW + hw0 + hw)) * CIN + c0 + seg);
        dst[0] = *(uint4*)&dw[0];
        dst[1] = *(uint4*)&dw[4];
    }
}

// ---------------------------------------------------------------- fused ----
// BM=256, BN=64, BK=128 (round-7 change: 18 fat steps instead of 36 — the
// per-step barrier-lockstep drain was ~45% of the round-6 kernel; halving
// step count halves it). 512 thr / 8 waves, wave tile 32(o) x 64(hw).
// LDS = As[2][256x128] (128 KB) + Bs[2][64x128] (32 KB) = 160 KiB exactly
// (AITER fmha precedent on gfx950). As double-buffered with 1-step DMA
// lead; completion enforced by counted vmcnt(8) at step entry (vmcnt(0) at
// the final step). Bs double-buffered, lerped one step ahead from corner
// regs gathered two steps ahead. Raw barrier (lgkmcnt(0)+s_barrier).
// MFMA as two 16-MFMA half-clusters (h0 then h1) to cap VGPR liveness.
__global__ __launch_bounds__(512, 2) void fused_kernel(const unsigned short* __restrict__ wbf,
                                                       const unsigned short* __restrict__ xtb,
                                                       const float* __restrict__ off,
                                                       float* __restrict__ out) {
    __shared__ unsigned short As[2][256 * 128];  // 128 KB
    __shared__ unsigned short Bs[2][64 * 128];   // 32 KB

    const int tid  = threadIdx.x;
    const int wv   = tid >> 6;                // 0..7  (M position, 32 rows each)
    const int lane = tid & 63;
    const int quad = lane >> 4;
    const int l15  = lane & 15;

    const int hw_local = tid >> 3;            // 0..63
    const int seg8     = tid & 7;             // 16-ch segment pair within 128

    // XCD-aware decode (gfx950 dispatch: consecutive ids round-robin XCDs)
    const int id  = blockIdx.x;
    const int n   = ((id & 7) << 1) | ((id >> 3) & 1);
    const int hw0 = (id >> 4) * 64;

    const int hw = hw0 + hw_local;
    const int h  = hw >> 5, w = hw & 31;

    // A staging lane pattern: 4 rows per async16 (row = 256 B), XOR swizzle
    // ch-slot = chunk ^ (row&7) encoded in the per-lane SOURCE address.
    const int srow4   = lane >> 4;            // 0..3
    const int schunk  = lane & 15;            // 0..15 (16 B chunks per row)

    const uint4*  xb4  = (const uint4*)(xtb + (size_t)n * HW * CIN);
    const float2* offp = (const float2*)(off + ((size_t)n * HW + hw) * (2 * KK));

    f32x4 acc[2][4] = {};

    auto setup2 = [&](float2 o, int tapv, float* wg, int* ix) {
        float py = (float)(h + tapv / 3 - 1) + o.x;
        float px = (float)(w + tapv % 3 - 1) + o.y;
        float y0f = floorf(py), x0f = floorf(px);
        float ly = py - y0f, lx = px - x0f;
        int y0 = (int)y0f, x0 = (int)x0f;
#pragma unroll
        for (int c2 = 0; c2 < 4; ++c2) {
            int yy = y0 + (c2 >> 1);
            int xx = x0 + (c2 & 1);
            float wy = (c2 >> 1) ? ly : 1.0f - ly;
            float wx = (c2 & 1) ? lx : 1.0f - lx;
            bool v = (yy >= 0) && (yy < HH) && (xx >= 0) && (xx < WW);
            wg[c2] = v ? wy * wx : 0.0f;
            int yc = yy < 0 ? 0 : (yy > HH - 1 ? HH - 1 : yy);
            int xc = xx < 0 ? 0 : (xx > WW - 1 ? WW - 1 : xx);
            ix[c2] = yc * WW + xc;
        }
    };

    // gather 16 ch (2 uint4) per corner for ch-half hf of the thread's taps
    auto loadc = [&](uint4 cr[2][4], const int* ix, int hf) {
#pragma unroll
        for (int c2 = 0; c2 < 4; ++c2) {
            size_t b = (size_t)ix[c2] * 32 + hf * 16 + seg8 * 2;
            cr[0][c2] = xb4[b];
            cr[1][c2] = xb4[b + 1];
        }
    };

    // DMA one 256x128 A tile (k-step s: ck base = s*128) into As[ai]
    auto dmaA = [&](int ai, int s) {
        unsigned short* dst = &As[ai][0];
        const unsigned short* wsrc = wbf + s * 128;
#pragma unroll
        for (int j = 0; j < 8; ++j) {
            int rb  = wv * 32 + j * 4;
            int row = rb + srow4;
            async16(wsrc + (size_t)row * CK + ((schunk ^ (row & 7)) * 8),
                    dst + rb * 128);
        }
    };

    auto lerpB = [&](int bi, const uint4 cr[2][4], const float* wg) {
#pragma unroll
        for (int p = 0; p < 2; ++p) {
            unsigned u0[4], u1[4], u2[4], u3[4];
            *(uint4*)u0 = cr[p][0]; *(uint4*)u1 = cr[p][1];
            *(uint4*)u2 = cr[p][2]; *(uint4*)u3 = cr[p][3];
            unsigned dw[4];
#pragma unroll
            for (int d = 0; d < 4; ++d) {
                float lo = wg[0] * bflo(u0[d]) + wg[1] * bflo(u1[d])
                         + wg[2] * bflo(u2[d]) + wg[3] * bflo(u3[d]);
                float hi = wg[0] * bfhi(u0[d]) + wg[1] * bfhi(u1[d])
                         + wg[2] * bfhi(u2[d]) + wg[3] * bfhi(u3[d]);
                dw[d] = pk2(lo, hi);
            }
            int c16 = seg8 * 2 + p;
            *(uint4*)&Bs[bi][hw_local * 128 + ((c16 ^ (hw_local & 7)) * 8)] = *(uint4*)dw;
        }
    };

    // frag reads for K-half h0 (64 of the 128 K): 4 A + 8 B ds_read_b128
    auto frag_read = [&](int ai, int bi, int h0, bf16x8 af[2][2], bf16x8 bfr[4][2]) {
        const unsigned short* Ap = &As[ai][0];
        const unsigned short* Bp = &Bs[bi][0];
#pragma unroll
        for (int mi = 0; mi < 2; ++mi)
#pragma unroll
            for (int hh = 0; hh < 2; ++hh) {
                int row = wv * 32 + mi * 16 + l15;
                int ch  = ((h0 * 2 + hh) * 4 + quad) ^ (row & 7);
                af[mi][hh] = *(const bf16x8*)(Ap + row * 128 + ch * 8);
            }
#pragma unroll
        for (int ni = 0; ni < 4; ++ni)
#pragma unroll
            for (int hh = 0; hh < 2; ++hh) {
                int row = ni * 16 + l15;
                int ch  = ((h0 * 2 + hh) * 4 + quad) ^ (row & 7);
                bfr[ni][hh] = *(const bf16x8*)(Bp + row * 128 + ch * 8);
            }
    };

    auto frag_mma = [&](bf16x8 af[2][2], bf16x8 bfr[4][2]) {
        __builtin_amdgcn_s_setprio(1);
#pragma unroll
        for (int mi = 0; mi < 2; ++mi)
#pragma unroll
            for (int ni = 0; ni < 4; ++ni) {
                acc[mi][ni] = __builtin_amdgcn_mfma_f32_16x16x32_bf16(af[mi][0], bfr[ni][0], acc[mi][ni], 0, 0, 0);
                acc[mi][ni] = __builtin_amdgcn_mfma_f32_16x16x32_bf16(af[mi][1], bfr[ni][1], acc[mi][ni], 0, 0, 0);
            }
        __builtin_amdgcn_s_setprio(0);
    };

    // ---- prologue: As[0]<-k0 (DMA), Bs[0]<-lerp(k0 half), crOd holds half1
    float wgc[4], wgn[4];
    int   ixc[4], ixn[4];
    uint4 crEv[2][4], crOd[2][4];
    float2 offv;
    {
        float2 o0 = offp[0];
        setup2(o0, 0, wgc, ixc);
        dmaA(0, 0);
        SB();
        loadc(crEv, ixc, 0);
        SB();
        lerpB(0, crEv, wgc);     // wait on crEv drains dmaA(0) (vmcnt FIFO)
        SB();
        loadc(crOd, ixc, 1);     // feeds step-0 lerp (B of step 1)
        offv = offp[1];          // issued now; value used at step-0 setup
        SYNC();
    }

    // ---- main loop: 18 K-steps (9 taps x 2 halves), 2 steps per iteration.
    // Step s: frag reads As[s&1]/Bs[s&1]; DMA fills As[(s+1)&1] for s+1;
    // lerp fills Bs[(s+1)&1] for s+1 from cr gathered at s-1.
#pragma unroll 1
    for (int t = 0; t < 9; ++t) {
        bf16x8 af[2][2], bfr[4][2];

        // ---- even step s=2t: buffers 0
        VM8();                               // drain dma of As[0]
        frag_read(0, 0, 0, af, bfr);
        SB();
        dmaA(1, 2 * t + 1);
        SB();
        if (t < 8) setup2(offv, t + 1, wgn, ixn);
        SB();
        lerpB(1, crOd, wgc);                 // B of step 2t+1 (tap t, half1)
        SB();
        if (t < 8) loadc(crEv, ixn, 0);      // for B of step 2t+2
        SB();
        frag_mma(af, bfr);
        frag_read(0, 0, 1, af, bfr);
        SB();
        frag_mma(af, bfr);
        SYNC();

        // ---- odd step s=2t+1: buffers 1
        if (t < 8) { VM8(); } else { VM0(); }   // t=8: no trailing loadc
        frag_read(1, 1, 0, af, bfr);
        SB();
        if (t < 7) offv = offp[t + 2];       // for setup at step 2t+2
        SB();
        if (t < 8) dmaA(0, 2 * t + 2);
        SB();
        if (t < 8) lerpB(0, crEv, wgn);      // B of step 2t+2 (tap t+1, half0)
        SB();
        if (t < 8) loadc(crOd, ixn, 1);      // for B of step 2t+3
        SB();
        frag_mma(af, bfr);
        frag_read(1, 1, 1, af, bfr);
        SB();
        frag_mma(af, bfr);
        if (t < 8) {
#pragma unroll
            for (int c2 = 0; c2 < 4; ++c2) wgc[c2] = wgn[c2];
            SYNC();
        }
    }

    // ---- epilogue: D layout col = lane&15, row = quad*4 + reg
    float* opnt = out + (size_t)n * COUT * HW + hw0;
#pragma unroll
    for (int mi = 0; mi < 2; ++mi)
#pragma unroll
        for (int ni = 0; ni < 4; ++ni) {
            int col = ni * 16 + l15;
#pragma unroll
            for (int rr = 0; rr < 4; ++rr) {
                int row = wv * 32 + mi * 16 + quad * 4 + rr;
                opnt[(size_t)row * HW + col] = acc[mi][ni][rr];
            }
        }
}

// --------------------------------------------------------------- launch ----
extern "C" void kernel_launch(void* const* d_in, const int* in_sizes, int n_in,
                              void* d_out, int out_size, void* d_ws, size_t ws_size,
                              hipStream_t stream) {
    const float* x   = (const float*)d_in[0];   // [16][256][32][32]
    const float* off = (const float*)d_in[1];   // [16][1024][18]
    const float* wt  = (const float*)d_in[2];   // [256][256][3][3]
    float* out = (float*)d_out;                 // [16][256][32][32]

    unsigned short* wbf = (unsigned short*)d_ws;                        // 1179648 B
    unsigned short* xtb = (unsigned short*)((char*)d_ws + 1179648);     // 8388608 B

    prep_kernel<<<1280, 256, 0, stream>>>(wt, wbf, x, xtb);
    fused_kernel<<<256, 512, 0, stream>>>(wbf, xtb, off, out);
}

// Round 8
// 115.488 us; speedup vs baseline: 1.0089x; 1.0089x over previous
//
#include <hip/hip_runtime.h>

// Problem constants
#define NB   16
#define CIN  256
#define COUT 256
#define HH   32
#define WW   32
#define HW   1024           // 32*32
#define KK   9
#define CK   2304           // CIN*KK  (ordered k*256 + c, tap-major)

typedef __bf16 bf16x8 __attribute__((ext_vector_type(8)));
typedef float  f32x4  __attribute__((ext_vector_type(4)));

__device__ __forceinline__ unsigned short f2bf(float f) {
    unsigned int u = __float_as_uint(f);
    u += 0x7FFFu + ((u >> 16) & 1u);          // round-nearest-even
    return (unsigned short)(u >> 16);
}
__device__ __forceinline__ float bfhi(unsigned int u) {   // high bf16 -> f32
    return __uint_as_float(u & 0xFFFF0000u);
}
__device__ __forceinline__ float bflo(unsigned int u) {   // low bf16 -> f32
    return __uint_as_float(u << 16);
}
// pack two f32 -> one dword of 2x bf16 (RNE). No builtin on gfx950 (ROCm 7.2)
// — inline asm v_cvt_pk_bf16_f32: src0 -> low 16, src1 -> high 16.
__device__ __forceinline__ unsigned pk2(float lo, float hi) {
    unsigned r;
    asm("v_cvt_pk_bf16_f32 %0, %1, %2" : "=v"(r) : "v"(lo), "v"(hi));
    return r;
}

typedef const __attribute__((address_space(1))) void* gas_ptr;
typedef __attribute__((address_space(3))) void* las_ptr;

__device__ __forceinline__ void async16(const void* g, void* l) {
    __builtin_amdgcn_global_load_lds((gas_ptr)g, (las_ptr)l, 16, 0, 0);
}

#define SB() __builtin_amdgcn_sched_barrier(0)
// Raw barrier: LDS-visibility only (B ds_write + frag reads). vmcnt is never
// drained to 0 in the loop — DMA completion is enforced by the counted
// vmcnt at step entry (below).
#define SYNC() do { SB(); asm volatile("s_waitcnt lgkmcnt(0)" ::: "memory"); SB(); \
                    __builtin_amdgcn_s_barrier(); SB(); } while (0)
// Counted VMEM waits (T4). At step entry, outstanding = [offp 0/1] + dma(8)
// + loadc(8).  vmcnt(8) drains the 8 DMA loads (they are always older than
// the trailing loadc batch) without waiting the fresh gathers.  The final
// step has no trailing loadc -> vmcnt(0).
#define VM8() do { SB(); asm volatile("s_waitcnt vmcnt(8)" ::: "memory"); SB(); } while (0)
#define VM0() do { SB(); asm volatile("s_waitcnt vmcnt(0)" ::: "memory"); SB(); } while (0)

// ----------------------------------------------------------------- prep ----
// One kernel, two roles (saves a launch and runs them concurrently):
//   blocks [0,256):    weight fp32 [O][C][3][3] -> bf16 [O][k*256+c]
//   blocks [256,1280): x fp32 [n][c][hw] -> xtb bf16 [n][hw][c] (64x64 tiles)
// Grid-barrier mono fusion measured WORSE (round 3) — keep two dispatches.
__global__ __launch_bounds__(256) void prep_kernel(const float* __restrict__ w,
                                                   unsigned short* __restrict__ wbf,
                                                   const float* __restrict__ x,
                                                   unsigned short* __restrict__ xtb) {
    __shared__ float lsbuf[64 * 65];
    const int t = threadIdx.x;

    if (blockIdx.x < 256) {
        // ---- wconv role
        const int o = blockIdx.x;
        const float* wo = w + (size_t)o * CK;
#pragma unroll
        for (int i = t; i < CK; i += 256) lsbuf[i] = wo[i];
        __syncthreads();
        unsigned short* dst = wbf + (size_t)o * CK;
#pragma unroll
        for (int i = t; i < CK; i += 256) {
            int k = i >> 8, c = i & 255;
            dst[i] = f2bf(lsbuf[c * KK + k]);     // bank stride 9: conflict-free
        }
        return;
    }

    // ---- xt role
    float (*ls)[65] = (float(*)[65])lsbuf;
    const int id  = blockIdx.x - 256;
    const int c0  = (id & 3) << 6;
    const int hw0 = ((id >> 2) & 15) << 6;
    const int n   = id >> 6;
    {
        int c = t >> 2, q = t & 3;
        const float4* base = (const float4*)(x + ((size_t)(n * CIN + c0 + c)) * HW + hw0 + q * 16);
#pragma unroll
        for (int j = 0; j < 4; ++j) {
            float4 v = base[j];
            ls[c][q * 16 + j * 4 + 0] = v.x;
            ls[c][q * 16 + j * 4 + 1] = v.y;
            ls[c][q * 16 + j * 4 + 2] = v.z;
            ls[c][q * 16 + j * 4 + 3] = v.w;
        }
    }
    __syncthreads();
    {
        int hw = t >> 2, seg = (t & 3) * 16;
        unsigned int dw[8];
#pragma unroll
        for (int j = 0; j < 8; ++j) {
            float f0 = ls[seg + 2 * j][hw];
            float f1 = ls[seg + 2 * j + 1][hw];
            dw[j] = (unsigned)f2bf(f0) | ((unsigned)f2bf(f1) << 16);
        }
        uint4* dst = (uint4*)(xtb + ((size_t)(n * HW + hw0 + hw)) * CIN + c0 + seg);
        dst[0] = *(uint4*)&dw[0];
        dst[1] = *(uint4*)&dw[4];
    }
}

// ---------------------------------------------------------------- fused ----
// BM=256, BN=64, BK=128, 18 fat steps. 512 thr / 8 waves, wave tile
// 32(o) x 64(hw). LDS = As[2][256x128] (128 KB) + Bs[2][64x128] (32 KB)
// = 160 KiB. As double-buffered, 1-step DMA lead, counted vmcnt(8) at step
// entry. Bs double-buffered, lerped one step ahead.
//
// Round-8 fix: B-write bank conflicts (4.1M in round 7). Each lerp thread
// now holds chunks {seg8, seg8+8} (loadc pairs +0/+8 uint4, not +0/+1), so
// one ds_write_b128 instruction's 8 writers cover all 8 bank-groups per
// row (slot&7 = seg8 ^ row&7) — the same conflict-free structure BK=64
// had. Swizzle function (kc ^ row&7) and all frag reads unchanged.
__global__ __launch_bounds__(512, 2) void fused_kernel(const unsigned short* __restrict__ wbf,
                                                       const unsigned short* __restrict__ xtb,
                                                       const float* __restrict__ off,
                                                       float* __restrict__ out) {
    __shared__ unsigned short As[2][256 * 128];  // 128 KB
    __shared__ unsigned short Bs[2][64 * 128];   // 32 KB

    const int tid  = threadIdx.x;
    const int wv   = tid >> 6;                // 0..7  (M position, 32 rows each)
    const int lane = tid & 63;
    const int quad = lane >> 4;
    const int l15  = lane & 15;

    const int hw_local = tid >> 3;            // 0..63
    const int seg8     = tid & 7;             // chunk id (0..7); pairs with +8

    // XCD-aware decode (gfx950 dispatch: consecutive ids round-robin XCDs)
    const int id  = blockIdx.x;
    const int n   = ((id & 7) << 1) | ((id >> 3) & 1);
    const int hw0 = (id >> 4) * 64;

    const int hw = hw0 + hw_local;
    const int h  = hw >> 5, w = hw & 31;

    // A staging lane pattern: 4 rows per async16 batch (row = 256 B), XOR
    // swizzle ch-slot = chunk ^ (row&7) encoded in the per-lane SOURCE addr.
    const int srow4   = lane >> 4;            // 0..3
    const int schunk  = lane & 15;            // 0..15 (16 B chunks per row)

    const uint4*  xb4  = (const uint4*)(xtb + (size_t)n * HW * CIN);
    const float2* offp = (const float2*)(off + ((size_t)n * HW + hw) * (2 * KK));

    f32x4 acc[2][4] = {};

    auto setup2 = [&](float2 o, int tapv, float* wg, int* ix) {
        float py = (float)(h + tapv / 3 - 1) + o.x;
        float px = (float)(w + tapv % 3 - 1) + o.y;
        float y0f = floorf(py), x0f = floorf(px);
        float ly = py - y0f, lx = px - x0f;
        int y0 = (int)y0f, x0 = (int)x0f;
#pragma unroll
        for (int c2 = 0; c2 < 4; ++c2) {
            int yy = y0 + (c2 >> 1);
            int xx = x0 + (c2 & 1);
            float wy = (c2 >> 1) ? ly : 1.0f - ly;
            float wx = (c2 & 1) ? lx : 1.0f - lx;
            bool v = (yy >= 0) && (yy < HH) && (xx >= 0) && (xx < WW);
            wg[c2] = v ? wy * wx : 0.0f;
            int yc = yy < 0 ? 0 : (yy > HH - 1 ? HH - 1 : yy);
            int xc = xx < 0 ? 0 : (xx > WW - 1 ? WW - 1 : xx);
            ix[c2] = yc * WW + xc;
        }
    };

    // gather 16 ch (2 uint4) per corner for ch-half hf: chunks seg8, seg8+8
    auto loadc = [&](uint4 cr[2][4], const int* ix, int hf) {
#pragma unroll
        for (int c2 = 0; c2 < 4; ++c2) {
            size_t b = (size_t)ix[c2] * 32 + hf * 16 + seg8;
            cr[0][c2] = xb4[b];
            cr[1][c2] = xb4[b + 8];
        }
    };

    // DMA one 256x128 A tile (k-step s: ck base = s*128) into As[ai]
    auto dmaA = [&](int ai, int s) {
        unsigned short* dst = &As[ai][0];
        const unsigned short* wsrc = wbf + s * 128;
#pragma unroll
        for (int j = 0; j < 8; ++j) {
            int rb  = wv * 32 + j * 4;
            int row = rb + srow4;
            async16(wsrc + (size_t)row * CK + ((schunk ^ (row & 7)) * 8),
                    dst + rb * 128);
        }
    };

    auto lerpB = [&](int bi, const uint4 cr[2][4], const float* wg) {
#pragma unroll
        for (int p = 0; p < 2; ++p) {
            unsigned u0[4], u1[4], u2[4], u3[4];
            *(uint4*)u0 = cr[p][0]; *(uint4*)u1 = cr[p][1];
            *(uint4*)u2 = cr[p][2]; *(uint4*)u3 = cr[p][3];
            unsigned dw[4];
#pragma unroll
            for (int d = 0; d < 4; ++d) {
                float lo = wg[0] * bflo(u0[d]) + wg[1] * bflo(u1[d])
                         + wg[2] * bflo(u2[d]) + wg[3] * bflo(u3[d]);
                float hi = wg[0] * bfhi(u0[d]) + wg[1] * bfhi(u1[d])
                         + wg[2] * bfhi(u2[d]) + wg[3] * bfhi(u3[d]);
                dw[d] = pk2(lo, hi);
            }
            int c16 = seg8 + p * 8;          // chunk id (matches loadc pairing)
            *(uint4*)&Bs[bi][hw_local * 128 + ((c16 ^ (hw_local & 7)) * 8)] = *(uint4*)dw;
        }
    };

    // frag reads for K-half h0 (64 of the 128 K): 4 A + 8 B ds_read_b128
    auto frag_read = [&](int ai, int bi, int h0, bf16x8 af[2][2], bf16x8 bfr[4][2]) {
        const unsigned short* Ap = &As[ai][0];
        const unsigned short* Bp = &Bs[bi][0];
#pragma unroll
        for (int mi = 0; mi < 2; ++mi)
#pragma unroll
            for (int hh = 0; hh < 2; ++hh) {
                int row = wv * 32 + mi * 16 + l15;
                int ch  = ((h0 * 2 + hh) * 4 + quad) ^ (row & 7);
                af[mi][hh] = *(const bf16x8*)(Ap + row * 128 + ch * 8);
            }
#pragma unroll
        for (int ni = 0; ni < 4; ++ni)
#pragma unroll
            for (int hh = 0; hh < 2; ++hh) {
                int row = ni * 16 + l15;
                int ch  = ((h0 * 2 + hh) * 4 + quad) ^ (row & 7);
                bfr[ni][hh] = *(const bf16x8*)(Bp + row * 128 + ch * 8);
            }
    };

    auto frag_mma = [&](bf16x8 af[2][2], bf16x8 bfr[4][2]) {
        __builtin_amdgcn_s_setprio(1);
#pragma unroll
        for (int mi = 0; mi < 2; ++mi)
#pragma unroll
            for (int ni = 0; ni < 4; ++ni) {
                acc[mi][ni] = __builtin_amdgcn_mfma_f32_16x16x32_bf16(af[mi][0], bfr[ni][0], acc[mi][ni], 0, 0, 0);
                acc[mi][ni] = __builtin_amdgcn_mfma_f32_16x16x32_bf16(af[mi][1], bfr[ni][1], acc[mi][ni], 0, 0, 0);
            }
        __builtin_amdgcn_s_setprio(0);
    };

    // ---- prologue: As[0]<-k0 (DMA), Bs[0]<-lerp(k0 half0), crOd holds half1
    float wgc[4], wgn[4];
    int   ixc[4], ixn[4];
    uint4 crEv[2][4], crOd[2][4];
    float2 offv;
    {
        float2 o0 = offp[0];
        setup2(o0, 0, wgc, ixc);
        dmaA(0, 0);
        SB();
        loadc(crEv, ixc, 0);
        SB();
        lerpB(0, crEv, wgc);     // wait on crEv drains dmaA(0) (vmcnt FIFO)
        SB();
        loadc(crOd, ixc, 1);     // feeds step-0 lerp (B of step 1)
        offv = offp[1];          // issued now; value used at step-0 setup
        SYNC();
    }

    // ---- main loop: 18 K-steps (9 taps x 2 halves), 2 steps per iteration.
    // Step s: frag reads As[s&1]/Bs[s&1]; DMA fills As[(s+1)&1] for s+1;
    // lerp fills Bs[(s+1)&1] for s+1 from cr gathered at s-1.
#pragma unroll 1
    for (int t = 0; t < 9; ++t) {
        bf16x8 af[2][2], bfr[4][2];

        // ---- even step s=2t: buffers 0
        VM8();                               // drain dma of As[0]
        frag_read(0, 0, 0, af, bfr);
        SB();
        dmaA(1, 2 * t + 1);
        SB();
        if (t < 8) setup2(offv, t + 1, wgn, ixn);
        SB();
        lerpB(1, crOd, wgc);                 // B of step 2t+1 (tap t, half1)
        SB();
        if (t < 8) loadc(crEv, ixn, 0);      // for B of step 2t+2
        SB();
        frag_mma(af, bfr);
        frag_read(0, 0, 1, af, bfr);
        SB();
        frag_mma(af, bfr);
        SYNC();

        // ---- odd step s=2t+1: buffers 1
        if (t < 8) { VM8(); } else { VM0(); }   // t=8: no trailing loadc
        frag_read(1, 1, 0, af, bfr);
        SB();
        if (t < 7) offv = offp[t + 2];       // for setup at step 2t+2
        SB();
        if (t < 8) dmaA(0, 2 * t + 2);
        SB();
        if (t < 8) lerpB(0, crEv, wgn);      // B of step 2t+2 (tap t+1, half0)
        SB();
        if (t < 8) loadc(crOd, ixn, 1);      // for B of step 2t+3
        SB();
        frag_mma(af, bfr);
        frag_read(1, 1, 1, af, bfr);
        SB();
        frag_mma(af, bfr);
        if (t < 8) {
#pragma unroll
            for (int c2 = 0; c2 < 4; ++c2) wgc[c2] = wgn[c2];
            SYNC();
        }
    }

    // ---- epilogue: D layout col = lane&15, row = quad*4 + reg
    float* opnt = out + (size_t)n * COUT * HW + hw0;
#pragma unroll
    for (int mi = 0; mi < 2; ++mi)
#pragma unroll
        for (int ni = 0; ni < 4; ++ni) {
            int col = ni * 16 + l15;
#pragma unroll
            for (int rr = 0; rr < 4; ++rr) {
                int row = wv * 32 + mi * 16 + quad * 4 + rr;
                opnt[(size_t)row * HW + col] = acc[mi][ni][rr];
            }
        }
}

// --------------------------------------------------------------- launch ----
extern "C" void kernel_launch(void* const* d_in, const int* in_sizes, int n_in,
                              void* d_out, int out_size, void* d_ws, size_t ws_size,
                              hipStream_t stream) {
    const float* x   = (const float*)d_in[0];   // [16][256][32][32]
    const float* off = (const float*)d_in[1];   // [16][1024][18]
    const float* wt  = (const float*)d_in[2];   // [256][256][3][3]
    float* out = (float*)d_out;                 // [16][256][32][32]

    unsigned short* wbf = (unsigned short*)d_ws;                        // 1179648 B
    unsigned short* xtb = (unsigned short*)((char*)d_ws + 1179648);     // 8388608 B

    prep_kernel<<<1280, 256, 0, stream>>>(wt, wbf, x, xtb);
    fused_kernel<<<256, 512, 0, stream>>>(wbf, xtb, off, out);
}